// Round 7
// baseline (1776.746 us; speedup 1.0000x reference)
//
#include <hip/hip_runtime.h>
#include <hip/hip_bf16.h>
#include <stdint.h>

// B=4, S=4096, D=2048. M = B*S = 16384 token rows.
// VERIFIED: inputs fp32 dict-order (probe R6), output fp32 (reference dtype),
// MFMA GEMM == VALU GEMM bit-identical (R3==R5), 3-phase scan == sequential
// scan bit-identical (R5==R6), ws_size >= 202 MB (R5 launched).
#define M_DIM 16384
#define N_DIM 2048
#define K_DIM 2048
#define S_LEN 4096
#define NCHUNK 64
#define CLEN 64
#define EPSV 1e-5f

typedef __hip_bfloat16 bf16;
typedef __attribute__((ext_vector_type(8))) short bf16x8;
typedef __attribute__((ext_vector_type(4))) float floatx4;

__device__ inline short f2b(float v) {
  __hip_bfloat16 h = __float2bfloat16(v);
  return *(short*)&h;
}

__device__ inline float sigm(float v) { return 1.f / (1.f + __expf(-v)); }

// Stage 128x32 tile from row-major fp32 global (ld elems) into bf16 LDS [128][32].
// 256 threads x 2 slots; 4 consecutive lanes cover one row's 32 k-elems.
__device__ inline void stage128x32f(const float* gtile, bf16* sbuf, size_t ld, int tid) {
#pragma unroll
  for (int j = 0; j < 2; ++j) {
    const int s = tid + j * 256;
    const int row = s >> 2;
    const int col = (s & 3) * 8;
    const float4 lo = *(const float4*)(gtile + (size_t)row * ld + col);
    const float4 hi = *(const float4*)(gtile + (size_t)row * ld + col + 4);
    bf16x8 v;
    v[0] = f2b(lo.x); v[1] = f2b(lo.y); v[2] = f2b(lo.z); v[3] = f2b(lo.w);
    v[4] = f2b(hi.x); v[5] = f2b(hi.y); v[6] = f2b(hi.z); v[7] = f2b(hi.w);
    *(bf16x8*)(sbuf + row * 32 + col) = v;
  }
}

__device__ inline bf16x8 fragld(const bf16* sbuf, int row, int ko) {
  return *(const bf16x8*)(sbuf + row * 32 + ko);
}

// ---------------- GEMM 1: i,f fused -> raw bf16 ----------------
__global__ __launch_bounds__(256) void k_gemm_if(
    const float* __restrict__ X, const float* __restrict__ Wi, const float* __restrict__ Wf,
    bf16* __restrict__ Ib, bf16* __restrict__ Fb) {
  __shared__ __align__(16) bf16 sA[128 * 32];
  __shared__ __align__(16) bf16 sI[128 * 32];
  __shared__ __align__(16) bf16 sF[128 * 32];
  const int tid = threadIdx.x, lane = tid & 63, w = tid >> 6;
  const int wm = w & 1, wn = w >> 1;
  const size_t bm = (size_t)blockIdx.y * 128, bn = (size_t)blockIdx.x * 128;
  const int kq = lane >> 4, kr = lane & 15;
  floatx4 ai[4][4], af[4][4];
#pragma unroll
  for (int p = 0; p < 4; ++p)
#pragma unroll
    for (int q = 0; q < 4; ++q) {
      ai[p][q] = floatx4{0.f, 0.f, 0.f, 0.f};
      af[p][q] = floatx4{0.f, 0.f, 0.f, 0.f};
    }
  for (int k0 = 0; k0 < K_DIM; k0 += 32) {
    stage128x32f(X + bm * K_DIM + k0, sA, K_DIM, tid);
    stage128x32f(Wi + bn * K_DIM + k0, sI, K_DIM, tid);
    stage128x32f(Wf + bn * K_DIM + k0, sF, K_DIM, tid);
    __syncthreads();
    bf16x8 fa[4], fi[4], ff[4];
#pragma unroll
    for (int t = 0; t < 4; ++t) {
      fa[t] = fragld(sA, wm * 64 + t * 16 + kr, kq * 8);
      fi[t] = fragld(sI, wn * 64 + t * 16 + kr, kq * 8);
      ff[t] = fragld(sF, wn * 64 + t * 16 + kr, kq * 8);
    }
#pragma unroll
    for (int p = 0; p < 4; ++p)
#pragma unroll
      for (int q = 0; q < 4; ++q) {
        ai[p][q] = __builtin_amdgcn_mfma_f32_16x16x32_bf16(fa[p], fi[q], ai[p][q], 0, 0, 0);
        af[p][q] = __builtin_amdgcn_mfma_f32_16x16x32_bf16(fa[p], ff[q], af[p][q], 0, 0, 0);
      }
    __syncthreads();
  }
#pragma unroll
  for (int p = 0; p < 4; ++p)
#pragma unroll
    for (int q = 0; q < 4; ++q)
#pragma unroll
      for (int r = 0; r < 4; ++r) {
        size_t m = bm + wm * 64 + p * 16 + kq * 4 + r;
        size_t n = bn + wn * 64 + q * 16 + kr;
        Ib[m * N_DIM + n] = __float2bfloat16(ai[p][q][r]);
        Fb[m * N_DIM + n] = __float2bfloat16(af[p][q][r]);
      }
}

// ---------------- GEMM 2: g -> raw bf16 ----------------
__global__ __launch_bounds__(256) void k_gemm_g(
    const float* __restrict__ X, const float* __restrict__ Wg, bf16* __restrict__ Gb) {
  __shared__ __align__(16) bf16 sA[128 * 32];
  __shared__ __align__(16) bf16 sB[128 * 32];
  const int tid = threadIdx.x, lane = tid & 63, w = tid >> 6;
  const int wm = w & 1, wn = w >> 1;
  const size_t bm = (size_t)blockIdx.y * 128, bn = (size_t)blockIdx.x * 128;
  const int kq = lane >> 4, kr = lane & 15;
  floatx4 ac[4][4];
#pragma unroll
  for (int p = 0; p < 4; ++p)
#pragma unroll
    for (int q = 0; q < 4; ++q) ac[p][q] = floatx4{0.f, 0.f, 0.f, 0.f};
  for (int k0 = 0; k0 < K_DIM; k0 += 32) {
    stage128x32f(X + bm * K_DIM + k0, sA, K_DIM, tid);
    stage128x32f(Wg + bn * K_DIM + k0, sB, K_DIM, tid);
    __syncthreads();
    bf16x8 fa[4], fb[4];
#pragma unroll
    for (int t = 0; t < 4; ++t) {
      fa[t] = fragld(sA, wm * 64 + t * 16 + kr, kq * 8);
      fb[t] = fragld(sB, wn * 64 + t * 16 + kr, kq * 8);
    }
#pragma unroll
    for (int p = 0; p < 4; ++p)
#pragma unroll
      for (int q = 0; q < 4; ++q)
        ac[p][q] = __builtin_amdgcn_mfma_f32_16x16x32_bf16(fa[p], fb[q], ac[p][q], 0, 0, 0);
    __syncthreads();
  }
#pragma unroll
  for (int p = 0; p < 4; ++p)
#pragma unroll
    for (int q = 0; q < 4; ++q)
#pragma unroll
      for (int r = 0; r < 4; ++r) {
        size_t m = bm + wm * 64 + p * 16 + kq * 4 + r;
        size_t n = bn + wn * 64 + q * 16 + kr;
        Gb[m * N_DIM + n] = __float2bfloat16(ac[p][q][r]);
      }
}

// ---------------- GEMM 3: out = (xg·Wo'^T) * r[m] -> FP32 ----------------
__global__ __launch_bounds__(256) void k_gemm_out(
    const bf16* __restrict__ XG, const bf16* __restrict__ WoS, const float* __restrict__ rbuf,
    float* __restrict__ Out) {
  __shared__ __align__(16) bf16 sA[128 * 32];
  __shared__ __align__(16) bf16 sB[128 * 32];
  const int tid = threadIdx.x, lane = tid & 63, w = tid >> 6;
  const int wm = w & 1, wn = w >> 1;
  const size_t bm = (size_t)blockIdx.y * 128, bn = (size_t)blockIdx.x * 128;
  const int kq = lane >> 4, kr = lane & 15;
  floatx4 ac[4][4];
#pragma unroll
  for (int p = 0; p < 4; ++p)
#pragma unroll
    for (int q = 0; q < 4; ++q) ac[p][q] = floatx4{0.f, 0.f, 0.f, 0.f};
  for (int k0 = 0; k0 < K_DIM; k0 += 32) {
#pragma unroll
    for (int j = 0; j < 2; ++j) {
      const int s = tid + j * 256;
      const int row = s >> 2;
      const int col = (s & 3) * 8;
      *(bf16x8*)(sA + row * 32 + col) = *(const bf16x8*)(XG + (bm + row) * K_DIM + k0 + col);
      *(bf16x8*)(sB + row * 32 + col) = *(const bf16x8*)(WoS + (bn + row) * K_DIM + k0 + col);
    }
    __syncthreads();
    bf16x8 fa[4], fb[4];
#pragma unroll
    for (int t = 0; t < 4; ++t) {
      fa[t] = fragld(sA, wm * 64 + t * 16 + kr, kq * 8);
      fb[t] = fragld(sB, wn * 64 + t * 16 + kr, kq * 8);
    }
#pragma unroll
    for (int p = 0; p < 4; ++p)
#pragma unroll
      for (int q = 0; q < 4; ++q)
        ac[p][q] = __builtin_amdgcn_mfma_f32_16x16x32_bf16(fa[p], fb[q], ac[p][q], 0, 0, 0);
    __syncthreads();
  }
#pragma unroll
  for (int p = 0; p < 4; ++p)
#pragma unroll
    for (int q = 0; q < 4; ++q)
#pragma unroll
      for (int r = 0; r < 4; ++r) {
        size_t m = bm + wm * 64 + p * 16 + kq * 4 + r;
        size_t n = bn + wn * 64 + q * 16 + kr;
        Out[m * N_DIM + n] = ac[p][q][r] * rbuf[m];   // FP32 store
      }
}

// ---------------- scan phase 1: per-chunk aggregates ----------------
__global__ __launch_bounds__(256) void k_scan1(const bf16* __restrict__ Ib, const bf16* __restrict__ Fb,
                                               float* __restrict__ aggP, float* __restrict__ aggH) {
  int t = blockIdx.x * 256 + threadIdx.x;
  int e = t & (N_DIM - 1);
  int rest = t >> 11;
  int b = rest & 3;
  int c = rest >> 2;
  size_t base = ((size_t)b * S_LEN + (size_t)c * CLEN) * N_DIM + e;
  float h = 0.f, P = 1.f;
  for (int s = 0; s < CLEN; ++s) {
    size_t i = base + (size_t)s * N_DIM;
    float iv = __bfloat162float(Ib[i]);
    float fv = __bfloat162float(Fb[i]);
    float a = sigm(fv);
    float bv = iv * sigm(iv) * (1.f - a);
    h = fmaf(a, h, bv);
    P *= a;
  }
  size_t row = (size_t)b * N_DIM + e;
  aggP[row * NCHUNK + c] = P;
  aggH[row * NCHUNK + c] = h;
}

// ---------------- scan phase 2: exclusive scan of chunk aggregates ----------------
__global__ __launch_bounds__(256) void k_scan2(float* __restrict__ aggP, float* __restrict__ aggH) {
  size_t row = (size_t)blockIdx.x * 256 + threadIdx.x;
  float carry = 0.f;
  size_t base = row * NCHUNK;
  for (int c = 0; c < NCHUNK; ++c) {
    float P = aggP[base + c], hh = aggH[base + c];
    aggP[base + c] = carry;
    carry = fmaf(P, carry, hh);
  }
}

// ---------------- scan phase 3: replay + gate, write xg over Ib ----------------
__global__ __launch_bounds__(256) void k_scan3(bf16* __restrict__ Ib, const bf16* __restrict__ Fb,
                                               const bf16* __restrict__ Gb, const float* __restrict__ aggPre) {
  int t = blockIdx.x * 256 + threadIdx.x;
  int e = t & (N_DIM - 1);
  int rest = t >> 11;
  int b = rest & 3;
  int c = rest >> 2;
  size_t base = ((size_t)b * S_LEN + (size_t)c * CLEN) * N_DIM + e;
  size_t row = (size_t)b * N_DIM + e;
  float h = aggPre[row * NCHUNK + c];
  for (int s = 0; s < CLEN; ++s) {
    size_t i = base + (size_t)s * N_DIM;
    float iv = __bfloat162float(Ib[i]);
    float fv = __bfloat162float(Fb[i]);
    float gv = __bfloat162float(Gb[i]);
    float a = sigm(fv);
    float bv = iv * sigm(iv) * (1.f - a);
    h = fmaf(a, h, bv);
    Ib[i] = __float2bfloat16(h * gv * sigm(gv));
  }
}

// ---------------- per-row rms scale ----------------
__global__ __launch_bounds__(256) void k_rownorm(const bf16* __restrict__ XG, float* __restrict__ rbuf) {
  size_t m = blockIdx.x;
  const bf16* rowp = XG + m * N_DIM;
  float ss = 0.f;
  for (int j = threadIdx.x; j < N_DIM; j += 256) {
    float v = __bfloat162float(rowp[j]);
    ss = fmaf(v, v, ss);
  }
#pragma unroll
  for (int off = 32; off > 0; off >>= 1) ss += __shfl_down(ss, off, 64);
  __shared__ float red[4];
  if ((threadIdx.x & 63) == 0) red[threadIdx.x >> 6] = ss;
  __syncthreads();
  if (threadIdx.x == 0) {
    float tot = red[0] + red[1] + red[2] + red[3];
    rbuf[m] = rsqrtf(tot * (1.f / N_DIM) + EPSV);
  }
}

// ---------------- Wo' = Wo * w_norm[e] (fp32 in, bf16 out) ----------------
__global__ __launch_bounds__(256) void k_woscale(const float* __restrict__ Wo, const float* __restrict__ wn,
                                                 bf16* __restrict__ WoS) {
  size_t i = (size_t)blockIdx.x * 256 + threadIdx.x;
  float v = Wo[i] * wn[i & (N_DIM - 1)];
  WoS[i] = __float2bfloat16(v);
}

extern "C" void kernel_launch(void* const* d_in, const int* in_sizes, int n_in,
                              void* d_out, int out_size, void* d_ws, size_t ws_size,
                              hipStream_t stream) {
  const float* x  = (const float*)d_in[0];
  const float* Wi = (const float*)d_in[1];
  const float* Wf = (const float*)d_in[2];
  const float* Wg = (const float*)d_in[3];
  const float* wn = (const float*)d_in[4];
  const float* Wo = (const float*)d_in[5];
  float* out = (float*)d_out;   // FP32 output (reference dtype)

  const size_t actB = (size_t)M_DIM * N_DIM * sizeof(bf16);
  char* ws = (char*)d_ws;
  bf16* Ibuf = (bf16*)ws;   ws += actB;   // raw i, later xg
  bf16* Fbuf = (bf16*)ws;   ws += actB;   // raw f
  bf16* Gbuf = (bf16*)ws;   ws += actB;   // raw g
  bf16* WoS  = (bf16*)ws;   ws += (size_t)N_DIM * K_DIM * sizeof(bf16);
  float* aggP = (float*)ws; ws += (size_t)4 * N_DIM * NCHUNK * sizeof(float);
  float* aggH = (float*)ws; ws += (size_t)4 * N_DIM * NCHUNK * sizeof(float);
  float* rbuf = (float*)ws; ws += (size_t)M_DIM * sizeof(float);
  if ((size_t)(ws - (char*)d_ws) > ws_size) return;

  dim3 gg(N_DIM / 128, M_DIM / 128), bb(256);
  k_gemm_if<<<gg, bb, 0, stream>>>(x, Wi, Wf, Ibuf, Fbuf);
  k_gemm_g<<<gg, bb, 0, stream>>>(x, Wg, Gbuf);
  k_woscale<<<(N_DIM * K_DIM) / 256, 256, 0, stream>>>(Wo, wn, WoS);
  k_scan1<<<(4 * N_DIM * NCHUNK) / 256, 256, 0, stream>>>(Ibuf, Fbuf, aggP, aggH);
  k_scan2<<<(4 * N_DIM) / 256, 256, 0, stream>>>(aggP, aggH);
  k_scan3<<<(4 * N_DIM * NCHUNK) / 256, 256, 0, stream>>>(Ibuf, Fbuf, Gbuf, aggP);
  k_rownorm<<<M_DIM, 256, 0, stream>>>(Ibuf, rbuf);
  k_gemm_out<<<gg, bb, 0, stream>>>(Ibuf, WoS, rbuf, out);
}

// Round 8
// 1298.037 us; speedup vs baseline: 1.3688x; 1.3688x over previous
//
#include <hip/hip_runtime.h>
#include <hip/hip_bf16.h>
#include <stdint.h>

// B=4, S=4096, D=2048. M = B*S = 16384 token rows.
// VERIFIED: inputs fp32 dict-order, OUTPUT FP32, MFMA layouts correct (R7 pass,
// absmax 0.03125). R7 baseline 1777 us; k_gemm_if 1005 us latency-bound
// (fp32 sync staging). This round: bf16 pre-convert + m97-style async
// global_load_lds staging + fused silu(g) epilogue (raw g never materialized).
#define M_DIM 16384
#define N_DIM 2048
#define K_DIM 2048
#define S_LEN 4096
#define NCHUNK 64
#define CLEN 64
#define EPSV 1e-5f

typedef __hip_bfloat16 bf16;
typedef __attribute__((ext_vector_type(8))) short bf16x8;
typedef __attribute__((ext_vector_type(4))) float floatx4;

__device__ inline short f2b(float v) {
  __hip_bfloat16 h = __float2bfloat16(v);
  return *(short*)&h;
}
__device__ inline float sigm(float v) { return 1.f / (1.f + __expf(-v)); }

// ---- async global->LDS, 16B/lane. LDS dest = wave-uniform base + lane*16. ----
__device__ inline void async_ld16(const bf16* g, bf16* l) {
  __builtin_amdgcn_global_load_lds(
      (__attribute__((address_space(1))) void*)(void*)g,
      (__attribute__((address_space(3))) void*)(void*)l, 16, 0, 0);
}

// Stage 128x32 bf16 tile from row-major global (ld elems) into LDS [128][32].
// Wave w covers rows [w*32, w*32+32) as 2 instrs of 16 rows. Address math:
// lane i -> LDS elem rseg*32 + 8i == row-major [rseg + (i>>2)][(i&3)*8]. ✓
__device__ inline void stage128x32(const bf16* gtile, bf16* sbuf, size_t ld, int lane, int w) {
#pragma unroll
  for (int j = 0; j < 2; ++j) {
    const int rseg = w * 32 + j * 16;
    const bf16* g = gtile + (size_t)(rseg + (lane >> 2)) * ld + (size_t)(lane & 3) * 8;
    async_ld16(g, sbuf + rseg * 32);
  }
}

__device__ inline bf16x8 fragld(const bf16* sbuf, int row, int ko) {
  return *(const bf16x8*)(sbuf + row * 32 + ko);
}

// ---------------- conversions ----------------
__global__ __launch_bounds__(256) void k_cvt_x(const float* __restrict__ X, bf16* __restrict__ Xb) {
  size_t i = ((size_t)blockIdx.x * 256 + threadIdx.x) * 8;
  const float4 lo = *(const float4*)(X + i);
  const float4 hi = *(const float4*)(X + i + 4);
  bf16x8 v;
  v[0] = f2b(lo.x); v[1] = f2b(lo.y); v[2] = f2b(lo.z); v[3] = f2b(lo.w);
  v[4] = f2b(hi.x); v[5] = f2b(hi.y); v[6] = f2b(hi.z); v[7] = f2b(hi.w);
  *(bf16x8*)(Xb + i) = v;
}

// Wi -> W1b, Wf -> W2b
__global__ __launch_bounds__(256) void k_cvt_wif(const float* __restrict__ Wi, const float* __restrict__ Wf,
                                                 bf16* __restrict__ W1b, bf16* __restrict__ W2b) {
  size_t i = ((size_t)blockIdx.x * 256 + threadIdx.x) * 8;
  {
    const float4 lo = *(const float4*)(Wi + i);
    const float4 hi = *(const float4*)(Wi + i + 4);
    bf16x8 v;
    v[0] = f2b(lo.x); v[1] = f2b(lo.y); v[2] = f2b(lo.z); v[3] = f2b(lo.w);
    v[4] = f2b(hi.x); v[5] = f2b(hi.y); v[6] = f2b(hi.z); v[7] = f2b(hi.w);
    *(bf16x8*)(W1b + i) = v;
  }
  {
    const float4 lo = *(const float4*)(Wf + i);
    const float4 hi = *(const float4*)(Wf + i + 4);
    bf16x8 v;
    v[0] = f2b(lo.x); v[1] = f2b(lo.y); v[2] = f2b(lo.z); v[3] = f2b(lo.w);
    v[4] = f2b(hi.x); v[5] = f2b(hi.y); v[6] = f2b(hi.z); v[7] = f2b(hi.w);
    *(bf16x8*)(W2b + i) = v;
  }
}

// Wg -> W1b (reuse), Wo*w_norm -> W2b (reuse). Runs after k_gemm_if (stream order).
__global__ __launch_bounds__(256) void k_cvt_g_wos(const float* __restrict__ Wg, const float* __restrict__ Wo,
                                                   const float* __restrict__ wn,
                                                   bf16* __restrict__ W1b, bf16* __restrict__ W2b) {
  size_t i = ((size_t)blockIdx.x * 256 + threadIdx.x) * 8;
  {
    const float4 lo = *(const float4*)(Wg + i);
    const float4 hi = *(const float4*)(Wg + i + 4);
    bf16x8 v;
    v[0] = f2b(lo.x); v[1] = f2b(lo.y); v[2] = f2b(lo.z); v[3] = f2b(lo.w);
    v[4] = f2b(hi.x); v[5] = f2b(hi.y); v[6] = f2b(hi.z); v[7] = f2b(hi.w);
    *(bf16x8*)(W1b + i) = v;
  }
  {
    const float4 lo = *(const float4*)(Wo + i);
    const float4 hi = *(const float4*)(Wo + i + 4);
    const int e = (int)(i & (N_DIM - 1));
    bf16x8 v;
    v[0] = f2b(lo.x * wn[e + 0]); v[1] = f2b(lo.y * wn[e + 1]);
    v[2] = f2b(lo.z * wn[e + 2]); v[3] = f2b(lo.w * wn[e + 3]);
    v[4] = f2b(hi.x * wn[e + 4]); v[5] = f2b(hi.y * wn[e + 5]);
    v[6] = f2b(hi.z * wn[e + 6]); v[7] = f2b(hi.w * wn[e + 7]);
    *(bf16x8*)(W2b + i) = v;
  }
}

// ---------------- GEMM 1: i,f fused (async staging) -> raw bf16 ----------------
__global__ __launch_bounds__(256) void k_gemm_if(
    const bf16* __restrict__ Xb, const bf16* __restrict__ Wib, const bf16* __restrict__ Wfb,
    bf16* __restrict__ Ib, bf16* __restrict__ Fb) {
  __shared__ __align__(16) bf16 sA[128 * 32];
  __shared__ __align__(16) bf16 sI[128 * 32];
  __shared__ __align__(16) bf16 sF[128 * 32];
  const int tid = threadIdx.x, lane = tid & 63, w = tid >> 6;
  const int wm = w & 1, wn = w >> 1;
  const size_t bm = (size_t)blockIdx.y * 128, bn = (size_t)blockIdx.x * 128;
  const int kq = lane >> 4, kr = lane & 15;
  floatx4 ai[4][4], af[4][4];
#pragma unroll
  for (int p = 0; p < 4; ++p)
#pragma unroll
    for (int q = 0; q < 4; ++q) {
      ai[p][q] = floatx4{0.f, 0.f, 0.f, 0.f};
      af[p][q] = floatx4{0.f, 0.f, 0.f, 0.f};
    }
  for (int k0 = 0; k0 < K_DIM; k0 += 32) {
    stage128x32(Xb + bm * K_DIM + k0, sA, K_DIM, lane, w);
    stage128x32(Wib + bn * K_DIM + k0, sI, K_DIM, lane, w);
    stage128x32(Wfb + bn * K_DIM + k0, sF, K_DIM, lane, w);
    __syncthreads();
    bf16x8 fa[4], fi[4], ff[4];
#pragma unroll
    for (int t = 0; t < 4; ++t) {
      fa[t] = fragld(sA, wm * 64 + t * 16 + kr, kq * 8);
      fi[t] = fragld(sI, wn * 64 + t * 16 + kr, kq * 8);
      ff[t] = fragld(sF, wn * 64 + t * 16 + kr, kq * 8);
    }
#pragma unroll
    for (int p = 0; p < 4; ++p)
#pragma unroll
      for (int q = 0; q < 4; ++q) {
        ai[p][q] = __builtin_amdgcn_mfma_f32_16x16x32_bf16(fa[p], fi[q], ai[p][q], 0, 0, 0);
        af[p][q] = __builtin_amdgcn_mfma_f32_16x16x32_bf16(fa[p], ff[q], af[p][q], 0, 0, 0);
      }
    __syncthreads();
  }
#pragma unroll
  for (int p = 0; p < 4; ++p)
#pragma unroll
    for (int q = 0; q < 4; ++q)
#pragma unroll
      for (int r = 0; r < 4; ++r) {
        size_t m = bm + wm * 64 + p * 16 + kq * 4 + r;
        size_t n = bn + wn * 64 + q * 16 + kr;
        Ib[m * N_DIM + n] = __float2bfloat16(ai[p][q][r]);
        Fb[m * N_DIM + n] = __float2bfloat16(af[p][q][r]);
      }
}

// ---------------- GEMM 2: g (async) + fused gate: xg = h * silu(g) -> Fb ----------------
__global__ __launch_bounds__(256) void k_gemm_g(
    const bf16* __restrict__ Xb, const bf16* __restrict__ Wgb, const bf16* __restrict__ Hb,
    bf16* __restrict__ XGout) {
  __shared__ __align__(16) bf16 sA[128 * 32];
  __shared__ __align__(16) bf16 sB[128 * 32];
  const int tid = threadIdx.x, lane = tid & 63, w = tid >> 6;
  const int wm = w & 1, wn = w >> 1;
  const size_t bm = (size_t)blockIdx.y * 128, bn = (size_t)blockIdx.x * 128;
  const int kq = lane >> 4, kr = lane & 15;
  floatx4 ac[4][4];
#pragma unroll
  for (int p = 0; p < 4; ++p)
#pragma unroll
    for (int q = 0; q < 4; ++q) ac[p][q] = floatx4{0.f, 0.f, 0.f, 0.f};
  for (int k0 = 0; k0 < K_DIM; k0 += 32) {
    stage128x32(Xb + bm * K_DIM + k0, sA, K_DIM, lane, w);
    stage128x32(Wgb + bn * K_DIM + k0, sB, K_DIM, lane, w);
    __syncthreads();
    bf16x8 fa[4], fb[4];
#pragma unroll
    for (int t = 0; t < 4; ++t) {
      fa[t] = fragld(sA, wm * 64 + t * 16 + kr, kq * 8);
      fb[t] = fragld(sB, wn * 64 + t * 16 + kr, kq * 8);
    }
#pragma unroll
    for (int p = 0; p < 4; ++p)
#pragma unroll
      for (int q = 0; q < 4; ++q)
        ac[p][q] = __builtin_amdgcn_mfma_f32_16x16x32_bf16(fa[p], fb[q], ac[p][q], 0, 0, 0);
    __syncthreads();
  }
#pragma unroll
  for (int p = 0; p < 4; ++p)
#pragma unroll
    for (int q = 0; q < 4; ++q)
#pragma unroll
      for (int r = 0; r < 4; ++r) {
        size_t m = bm + wm * 64 + p * 16 + kq * 4 + r;
        size_t n = bn + wn * 64 + q * 16 + kr;
        float gv = ac[p][q][r];
        float hv = __bfloat162float(Hb[m * N_DIM + n]);
        XGout[m * N_DIM + n] = __float2bfloat16(hv * gv * sigm(gv));
      }
}

// ---------------- GEMM 3: out = (xg·Wo'^T) * r[m] -> FP32 (async) ----------------
__global__ __launch_bounds__(256) void k_gemm_o(
    const bf16* __restrict__ XG, const bf16* __restrict__ WoS, const float* __restrict__ rbuf,
    float* __restrict__ Out) {
  __shared__ __align__(16) bf16 sA[128 * 32];
  __shared__ __align__(16) bf16 sB[128 * 32];
  const int tid = threadIdx.x, lane = tid & 63, w = tid >> 6;
  const int wm = w & 1, wn = w >> 1;
  const size_t bm = (size_t)blockIdx.y * 128, bn = (size_t)blockIdx.x * 128;
  const int kq = lane >> 4, kr = lane & 15;
  floatx4 ac[4][4];
#pragma unroll
  for (int p = 0; p < 4; ++p)
#pragma unroll
    for (int q = 0; q < 4; ++q) ac[p][q] = floatx4{0.f, 0.f, 0.f, 0.f};
  for (int k0 = 0; k0 < K_DIM; k0 += 32) {
    stage128x32(XG + bm * K_DIM + k0, sA, K_DIM, lane, w);
    stage128x32(WoS + bn * K_DIM + k0, sB, K_DIM, lane, w);
    __syncthreads();
    bf16x8 fa[4], fb[4];
#pragma unroll
    for (int t = 0; t < 4; ++t) {
      fa[t] = fragld(sA, wm * 64 + t * 16 + kr, kq * 8);
      fb[t] = fragld(sB, wn * 64 + t * 16 + kr, kq * 8);
    }
#pragma unroll
    for (int p = 0; p < 4; ++p)
#pragma unroll
      for (int q = 0; q < 4; ++q)
        ac[p][q] = __builtin_amdgcn_mfma_f32_16x16x32_bf16(fa[p], fb[q], ac[p][q], 0, 0, 0);
    __syncthreads();
  }
#pragma unroll
  for (int p = 0; p < 4; ++p)
#pragma unroll
    for (int q = 0; q < 4; ++q)
#pragma unroll
      for (int r = 0; r < 4; ++r) {
        size_t m = bm + wm * 64 + p * 16 + kq * 4 + r;
        size_t n = bn + wn * 64 + q * 16 + kr;
        Out[m * N_DIM + n] = ac[p][q][r] * rbuf[m];
      }
}

// ---------------- scan: 3-phase, emits h (bf16) over Ib ----------------
__global__ __launch_bounds__(256) void k_scan1(const bf16* __restrict__ Ib, const bf16* __restrict__ Fb,
                                               float* __restrict__ aggP, float* __restrict__ aggH) {
  int t = blockIdx.x * 256 + threadIdx.x;
  int e = t & (N_DIM - 1);
  int rest = t >> 11;
  int b = rest & 3;
  int c = rest >> 2;
  size_t base = ((size_t)b * S_LEN + (size_t)c * CLEN) * N_DIM + e;
  float h = 0.f, P = 1.f;
  for (int s = 0; s < CLEN; ++s) {
    size_t i = base + (size_t)s * N_DIM;
    float iv = __bfloat162float(Ib[i]);
    float fv = __bfloat162float(Fb[i]);
    float a = sigm(fv);
    float bv = iv * sigm(iv) * (1.f - a);
    h = fmaf(a, h, bv);
    P *= a;
  }
  size_t row = (size_t)b * N_DIM + e;
  aggP[row * NCHUNK + c] = P;
  aggH[row * NCHUNK + c] = h;
}

__global__ __launch_bounds__(256) void k_scan2(float* __restrict__ aggP, float* __restrict__ aggH) {
  size_t row = (size_t)blockIdx.x * 256 + threadIdx.x;
  float carry = 0.f;
  size_t base = row * NCHUNK;
  for (int c = 0; c < NCHUNK; ++c) {
    float P = aggP[base + c], hh = aggH[base + c];
    aggP[base + c] = carry;
    carry = fmaf(P, carry, hh);
  }
}

__global__ __launch_bounds__(256) void k_scan3(bf16* __restrict__ Ib, const bf16* __restrict__ Fb,
                                               const float* __restrict__ aggPre) {
  int t = blockIdx.x * 256 + threadIdx.x;
  int e = t & (N_DIM - 1);
  int rest = t >> 11;
  int b = rest & 3;
  int c = rest >> 2;
  size_t base = ((size_t)b * S_LEN + (size_t)c * CLEN) * N_DIM + e;
  size_t row = (size_t)b * N_DIM + e;
  float h = aggPre[row * NCHUNK + c];
  for (int s = 0; s < CLEN; ++s) {
    size_t i = base + (size_t)s * N_DIM;
    float iv = __bfloat162float(Ib[i]);
    float fv = __bfloat162float(Fb[i]);
    float a = sigm(fv);
    float bv = iv * sigm(iv) * (1.f - a);
    h = fmaf(a, h, bv);
    Ib[i] = __float2bfloat16(h);   // h (gating applied in k_gemm_g epilogue)
  }
}

// ---------------- per-row rms scale over xg (in Fb) ----------------
__global__ __launch_bounds__(256) void k_rownorm(const bf16* __restrict__ XG, float* __restrict__ rbuf) {
  size_t m = blockIdx.x;
  const bf16* rowp = XG + m * N_DIM;
  float ss = 0.f;
  for (int j = threadIdx.x; j < N_DIM; j += 256) {
    float v = __bfloat162float(rowp[j]);
    ss = fmaf(v, v, ss);
  }
#pragma unroll
  for (int off = 32; off > 0; off >>= 1) ss += __shfl_down(ss, off, 64);
  __shared__ float red[4];
  if ((threadIdx.x & 63) == 0) red[threadIdx.x >> 6] = ss;
  __syncthreads();
  if (threadIdx.x == 0) {
    float tot = red[0] + red[1] + red[2] + red[3];
    rbuf[m] = rsqrtf(tot * (1.f / N_DIM) + EPSV);
  }
}

extern "C" void kernel_launch(void* const* d_in, const int* in_sizes, int n_in,
                              void* d_out, int out_size, void* d_ws, size_t ws_size,
                              hipStream_t stream) {
  const float* x  = (const float*)d_in[0];
  const float* Wi = (const float*)d_in[1];
  const float* Wf = (const float*)d_in[2];
  const float* Wg = (const float*)d_in[3];
  const float* wn = (const float*)d_in[4];
  const float* Wo = (const float*)d_in[5];
  float* out = (float*)d_out;

  const size_t actB = (size_t)M_DIM * N_DIM * sizeof(bf16);   // 64 MiB
  const size_t wB   = (size_t)N_DIM * K_DIM * sizeof(bf16);   // 8 MiB
  char* ws = (char*)d_ws;
  bf16* Xb  = (bf16*)ws;    ws += actB;   // x in bf16
  bf16* Ibuf= (bf16*)ws;    ws += actB;   // raw i -> h
  bf16* Fbuf= (bf16*)ws;    ws += actB;   // raw f -> xg
  bf16* W1b = (bf16*)ws;    ws += wB;     // Wi, later Wg
  bf16* W2b = (bf16*)ws;    ws += wB;     // Wf, later Wo*w_norm
  float* aggP = (float*)ws; ws += (size_t)4 * N_DIM * NCHUNK * sizeof(float);
  float* aggH = (float*)ws; ws += (size_t)4 * N_DIM * NCHUNK * sizeof(float);
  float* rbuf = (float*)ws; ws += (size_t)M_DIM * sizeof(float);
  if ((size_t)(ws - (char*)d_ws) > ws_size) return;  // detectable: absmax 5.625

  dim3 gg(N_DIM / 128, M_DIM / 128), bb(256);
  k_cvt_x  <<<(M_DIM * (size_t)K_DIM) / (256 * 8), 256, 0, stream>>>(x, Xb);
  k_cvt_wif<<<((size_t)N_DIM * K_DIM) / (256 * 8), 256, 0, stream>>>(Wi, Wf, W1b, W2b);
  k_gemm_if<<<gg, bb, 0, stream>>>(Xb, W1b, W2b, Ibuf, Fbuf);
  k_scan1  <<<(4 * N_DIM * NCHUNK) / 256, 256, 0, stream>>>(Ibuf, Fbuf, aggP, aggH);
  k_scan2  <<<(4 * N_DIM) / 256, 256, 0, stream>>>(aggP, aggH);
  k_scan3  <<<(4 * N_DIM * NCHUNK) / 256, 256, 0, stream>>>(Ibuf, Fbuf, aggP);
  k_cvt_g_wos<<<((size_t)N_DIM * K_DIM) / (256 * 8), 256, 0, stream>>>(Wg, Wo, wn, W1b, W2b);
  k_gemm_g <<<gg, bb, 0, stream>>>(Xb, W1b, Ibuf, Fbuf);   // xg -> Fbuf
  k_rownorm<<<M_DIM, 256, 0, stream>>>(Fbuf, rbuf);
  k_gemm_o <<<gg, bb, 0, stream>>>(Fbuf, W2b, rbuf, out);
}